// Round 1
// baseline (1336.517 us; speedup 1.0000x reference)
//
#include <hip/hip_runtime.h>
#include <stdint.h>

#define NSTEPS 64
#define NHID 256
#define NKEYS 512
#define KTOP 16
#define BSZ 32

typedef __bf16 bf16x8 __attribute__((ext_vector_type(8)));
typedef float f32x4 __attribute__((ext_vector_type(4)));

__device__ __forceinline__ uint32_t rne_bf16(uint32_t u) {
  // round-to-nearest-even fp32 -> bf16 (finite inputs only)
  return (u + 0x7FFFu + ((u >> 16) & 1u)) >> 16;
}

// split 8 consecutive floats into bf16 hi (RNE) and bf16 lo (residual, RNE)
__device__ __forceinline__ void split8_u(const float* f, uint4& h4, uint4& l4) {
  uint32_t uh[4], ul[4];
#pragma unroll
  for (int i = 0; i < 4; ++i) {
    float a = f[2 * i], b = f[2 * i + 1];
    uint32_t ua = __builtin_bit_cast(uint32_t, a);
    uint32_t ub = __builtin_bit_cast(uint32_t, b);
    uint32_t ha = rne_bf16(ua), hb = rne_bf16(ub);
    uh[i] = ha | (hb << 16);
    float fa = __builtin_bit_cast(float, ha << 16);
    float fb = __builtin_bit_cast(float, hb << 16);
    uint32_t la = rne_bf16(__builtin_bit_cast(uint32_t, a - fa));
    uint32_t lb = rne_bf16(__builtin_bit_cast(uint32_t, b - fb));
    ul[i] = la | (lb << 16);
  }
  h4 = make_uint4(uh[0], uh[1], uh[2], uh[3]);
  l4 = make_uint4(ul[0], ul[1], ul[2], ul[3]);
}

__device__ __forceinline__ f32x4 mfma16(bf16x8 a, bf16x8 b, f32x4 c) {
  return __builtin_amdgcn_mfma_f32_16x16x32_bf16(a, b, c, 0, 0, 0);
}

// Block: 256 threads (4 waves). blockIdx.y = b, blockIdx.x = chunk of 16 n.
// Each wave independently handles 4 n values: streams K_{n,b} (64x256 fp32)
// from global, splits to bf16 hi/lo, and does S = Q.K^T via 3-term split MFMA.
// Q_b is staged once per block into LDS as bf16 hi/lo (XOR-swizzled groups).
__global__ __launch_bounds__(256, 2)
void cache_score_kernel(const float* __restrict__ query,
                        const float* __restrict__ keys,
                        float* __restrict__ out) {
  __shared__ uint32_t qh_l[64 * 128];  // 32 KB: 64 rows x 32 groups x 4 u32
  __shared__ uint32_t ql_l[64 * 128];  // 32 KB

  const int tid = threadIdx.x;
  const int b = blockIdx.y;

  // ---- stage Q_b (query[0, i, b, :]) into LDS ----
  {
    const int r = tid >> 2;   // row i: 0..63 (4 threads per row)
    const int q4 = tid & 3;
    const float* qrow = query + (size_t)r * (BSZ * NHID) + (size_t)b * NHID;
#pragma unroll
    for (int u = 0; u < 8; ++u) {
      const int g = q4 + 4 * u;  // group of 8 cols, 0..31
      const float4* src = (const float4*)(qrow + g * 8);
      float4 A = src[0], B = src[1];
      float f[8] = {A.x, A.y, A.z, A.w, B.x, B.y, B.z, B.w};
      uint4 h4, l4;
      split8_u(f, h4, l4);
      const int gp = g ^ (r & 7);  // XOR swizzle: 16B-aligned, ~2-way banks
      *(uint4*)&qh_l[r * 128 + gp * 4] = h4;
      *(uint4*)&ql_l[r * 128 + gp * 4] = l4;
    }
  }
  __syncthreads();

  const int wave = tid >> 6;
  const int lane = tid & 63;
  const int m = lane & 15;    // fragment row index
  const int g8 = lane >> 4;   // k-subgroup 0..3
  const int n0 = blockIdx.x * 16 + wave * 4;

  for (int u = 0; u < 4; ++u) {
    const int n = n0 + u;
    // keys[n, b, j*256 + h]; lane covers rows j = 16*jt + m, cols g8*8..
    const float* kb = keys + ((size_t)n * BSZ + b) * (NSTEPS * NHID)
                      + (size_t)m * NHID + g8 * 8;

    f32x4 acc[4][4];  // [i-tile][j-tile]
#pragma unroll
    for (int it = 0; it < 4; ++it)
#pragma unroll
      for (int jt = 0; jt < 4; ++jt)
        acc[it][jt] = (f32x4){0.f, 0.f, 0.f, 0.f};

    float4 cur[4][2];
#pragma unroll
    for (int jt = 0; jt < 4; ++jt) {
      const float4* p = (const float4*)(kb + jt * (16 * NHID));
      cur[jt][0] = p[0];
      cur[jt][1] = p[1];
    }

    for (int s = 0; s < 8; ++s) {  // K = 256 in steps of 32
      float4 nxt[4][2];
      if (s < 7) {
#pragma unroll
        for (int jt = 0; jt < 4; ++jt) {
          const float4* p = (const float4*)(kb + jt * (16 * NHID) + (s + 1) * 32);
          nxt[jt][0] = p[0];
          nxt[jt][1] = p[1];
        }
      }
      bf16x8 bh[4], bl[4];
#pragma unroll
      for (int jt = 0; jt < 4; ++jt) {
        float f[8] = {cur[jt][0].x, cur[jt][0].y, cur[jt][0].z, cur[jt][0].w,
                      cur[jt][1].x, cur[jt][1].y, cur[jt][1].z, cur[jt][1].w};
        uint4 h4, l4;
        split8_u(f, h4, l4);
        bh[jt] = __builtin_bit_cast(bf16x8, h4);
        bl[jt] = __builtin_bit_cast(bf16x8, l4);
      }
#pragma unroll
      for (int it = 0; it < 4; ++it) {
        const int row = 16 * it + m;
        const int gp = (4 * s + g8) ^ (m & 7);  // row&7 == m&7
        bf16x8 ah = *(const bf16x8*)&qh_l[row * 128 + gp * 4];
        bf16x8 al = *(const bf16x8*)&ql_l[row * 128 + gp * 4];
#pragma unroll
        for (int jt = 0; jt < 4; ++jt) {
          acc[it][jt] = mfma16(ah, bh[jt], acc[it][jt]);
          acc[it][jt] = mfma16(ah, bl[jt], acc[it][jt]);
          acc[it][jt] = mfma16(al, bh[jt], acc[it][jt]);
        }
      }
      if (s < 7) {
#pragma unroll
        for (int jt = 0; jt < 4; ++jt) {
          cur[jt][0] = nxt[jt][0];
          cur[jt][1] = nxt[jt][1];
        }
      }
    }

    // max over the full 64x64 S tile (layout irrelevant for a max)
    float mx = -INFINITY;
#pragma unroll
    for (int it = 0; it < 4; ++it)
#pragma unroll
      for (int jt = 0; jt < 4; ++jt) {
        mx = fmaxf(mx, fmaxf(fmaxf(acc[it][jt][0], acc[it][jt][1]),
                             fmaxf(acc[it][jt][2], acc[it][jt][3])));
      }
#pragma unroll
    for (int off = 32; off >= 1; off >>= 1)
      mx = fmaxf(mx, __shfl_xor(mx, off, 64));
    if (lane == 0) out[(size_t)b * NKEYS + n] = mx;
  }
}

// One wave per batch: iterative top-16 (descending, ties -> lowest index),
// matching jax.lax.top_k. Indices written as floats.
__global__ __launch_bounds__(64)
void topk_kernel(const float* __restrict__ att, float* __restrict__ out) {
  const int b = blockIdx.x;
  const int lane = threadIdx.x;
  float v[8];
#pragma unroll
  for (int u = 0; u < 8; ++u) v[u] = att[b * NKEYS + u * 64 + lane];
#pragma unroll
  for (int k = 0; k < KTOP; ++k) {
    float bv = -INFINITY;
    int bi = 0x7FFFFFFF;
#pragma unroll
    for (int u = 0; u < 8; ++u) {
      if (v[u] > bv) { bv = v[u]; bi = u * 64 + lane; }  // ascending idx, strict >
    }
#pragma unroll
    for (int off = 32; off >= 1; off >>= 1) {
      float ov = __shfl_xor(bv, off, 64);
      int oi = __shfl_xor(bi, off, 64);
      if (ov > bv || (ov == bv && oi < bi)) { bv = ov; bi = oi; }
    }
    if (lane == 0) out[BSZ * NKEYS + k * BSZ + b] = (float)bi;
#pragma unroll
    for (int u = 0; u < 8; ++u)
      if (u * 64 + lane == bi) v[u] = -INFINITY;
  }
}

extern "C" void kernel_launch(void* const* d_in, const int* in_sizes, int n_in,
                              void* d_out, int out_size, void* d_ws, size_t ws_size,
                              hipStream_t stream) {
  const float* query = (const float*)d_in[0];  // (1, 64, 32, 256) fp32
  const float* keys = (const float*)d_in[1];   // (512, 32, 16384) fp32
  float* out = (float*)d_out;                  // 16384 att + 512 idx (as float)

  dim3 grid(NKEYS / 16, BSZ);  // 32 x 32 blocks
  cache_score_kernel<<<grid, 256, 0, stream>>>(query, keys, out);
  topk_kernel<<<BSZ, 64, 0, stream>>>(out, out);
}